// Round 5
// baseline (401.312 us; speedup 1.0000x reference)
//
#include <hip/hip_runtime.h>

#define EPS_F 0.1f
#define A_F 100.0f
#define NUMNEG_F 10.0f
#define EXP_EPS 1.1051709f   // e^0.1; gate: dist<EPS  <=>  (-inner + s) < e^EPS
#define CAP 64               // per-node capacity; two-sided deg ~ Poisson(20)
#define BATCH 16
#define NBLOCKS 4096

// ---- K1: two-sided bucket fill. No grad zeroing needed (node_kernel writes
//      every row exactly once); only zero any padding tail of d_out. ----
__global__ __launch_bounds__(256) void fill_kernel(
    const int* __restrict__ u_idx, const int* __restrict__ v_idx,
    int* __restrict__ counts, int* __restrict__ entries,
    float* __restrict__ out, int out_n, int grad_end, int E)
{
    const int tid = blockIdx.x * blockDim.x + threadIdx.x;
    const int nth = gridDim.x * blockDim.x;

    // zero only [grad_end, out_n) padding (usually empty)
    for (int i = grad_end + tid; i < out_n; i += nth) out[i] = 0.f;

    // each edge listed under BOTH endpoints (two independent chains/thread)
    for (int i = tid; i < E; i += nth) {
        const int u = u_idx[i], v = v_idx[i];
        const int s1 = atomicAdd(&counts[u], 1);
        const int s2 = atomicAdd(&counts[v], 1);
        if (s1 < CAP) entries[(size_t)u * CAP + s1] = v;
        if (s2 < CAP) entries[(size_t)v * CAP + s2] = u;
    }
}

// fold-merge: reduce two edges' partial-product vectors one level.
__device__ __forceinline__ float red2(float a, float b, int dist, bool sel) {
    const float fa = a + __shfl_xor(a, dist, 64);
    const float fb = b + __shfl_xor(b, dist, 64);
    return sel ? fb : fa;
}

// ---- K2: one wave per node n over its FULL (two-sided) neighbor list.
//      All grad[n] contributions accumulate in registers -> ONE plain
//      coalesced 256B store per node. Zero atomics. Transpose-reduce puts
//      edge e's inner in lane group e; epilogue lane-parallel. ----
__global__ __launch_bounds__(256) void node_kernel(
    const float* __restrict__ x,
    const int* __restrict__ counts,
    const int* __restrict__ entries,
    float* __restrict__ out,          // out[0]=energy, out+1 = grad
    float* __restrict__ block_energy,
    int N)
{
    const int lane = threadIdx.x & 63;
    const int wib  = threadIdx.x >> 6;
    const int wave = (blockIdx.x * blockDim.x + threadIdx.x) >> 6;
    const int nwaves = (gridDim.x * blockDim.x) >> 6;
    const float sign = (lane == 0) ? -1.0f : 1.0f;   // Minkowski J
    float* __restrict__ grad = out + 1;

    // hoisted select masks for the reduce tree
    const bool m32 = (lane & 32) != 0;
    const bool m16 = (lane & 16) != 0;
    const bool m8  = (lane & 8)  != 0;
    const bool m4  = (lane & 4)  != 0;
    const int  e4  = lane >> 2;      // which edge of the batch this lane handles

    float eacc = 0.0f;   // every edge counted from both sides, 4x lanes -> *0.125

    // prefetch first node's adjacency
    int u = wave;
    int deg = 0, myv = 0;
    if (u < N) {
        deg = counts[u];
        myv = entries[(size_t)u * CAP + lane];  // unconditional; masked by deg
    }

    while (u < N) {
        const int deg_c = min(deg, CAP);
        const int myv_c = myv;
        const float xuj = x[(size_t)u * 64 + lane] * sign;  // xu * J

        // prefetch next node's adjacency (overlaps with this node's gathers)
        const int un = u + nwaves;
        if (un < N) {
            deg = counts[un];
            myv = entries[(size_t)un * CAP + lane];
        }

        float gacc = 0.0f;
        for (int k0 = 0; k0 < deg_c; k0 += BATCH) {
            const int bn = min(BATCH, deg_c - k0);

            float xv[BATCH], p[BATCH];
            #pragma unroll
            for (int k = 0; k < BATCH; k++) {
                if (k < bn) {
                    const int vk = __builtin_amdgcn_readlane(myv_c, k0 + k);
                    xv[k] = x[(size_t)vk * 64 + lane];
                    p[k]  = xuj * xv[k];
                } else { xv[k] = 0.0f; p[k] = 0.0f; }
            }

            // transpose-reduce: 16 dots -> edge e at lanes 4e..4e+3
            float q0 = red2(p[0], p[8],  32, m32);
            float q1 = red2(p[1], p[9],  32, m32);
            float q2 = red2(p[2], p[10], 32, m32);
            float q3 = red2(p[3], p[11], 32, m32);
            float q4 = red2(p[4], p[12], 32, m32);
            float q5 = red2(p[5], p[13], 32, m32);
            float q6 = red2(p[6], p[14], 32, m32);
            float q7 = red2(p[7], p[15], 32, m32);
            float r0 = red2(q0, q4, 16, m16);
            float r1 = red2(q1, q5, 16, m16);
            float r2 = red2(q2, q6, 16, m16);
            float r3 = red2(q3, q7, 16, m16);
            float s0 = red2(r0, r2, 8, m8);
            float s1 = red2(r1, r3, 8, m8);
            float t0 = red2(s0, s1, 4, m4);
            t0 += __shfl_xor(t0, 2, 64);
            t0 += __shfl_xor(t0, 1, 64);
            // t0 = inner(edge e4), replicated over each 4-lane group

            // lane-parallel epilogue (one edge per 4-lane group)
            const float inner = fminf(t0, -1.0f - 1e-7f);
            const float s     = __builtin_amdgcn_sqrtf(fmaf(inner, inner, -1.0f));
            const float t     = s - inner;                  // dist = log(t)
            const bool  act   = (t < EXP_EPS) & (e4 < bn);
            const float dist  = __logf(t);
            const float delta = act ? (EPS_F - dist) : 0.0f;
            eacc = fmaf(delta, delta, eacc);
            const float factor = (-(A_F / NUMNEG_F)) * delta *
                                 __builtin_amdgcn_rcpf(s + 1e-9f);  // 0 if !act

            // accumulate this node's gradient (register only — no scatter)
            const unsigned long long ball = __ballot(act);
            #pragma unroll
            for (int k = 0; k < BATCH; k++) {
                if ((ball >> (4 * k)) & 1ull) {
                    const float fk = __uint_as_float(
                        __builtin_amdgcn_readlane(__float_as_uint(factor), 4 * k));
                    gacc = fmaf(fk, xv[k], gacc);
                }
            }
        }

        // ONE plain coalesced 256B store per node (unconditional: deg 0 -> 0)
        grad[(size_t)u * 64 + lane] = gacc * sign;
        u = un;
    }

    // wave-reduce energy (each edge seen from both sides on 4 lanes -> *0.125)
    #pragma unroll
    for (int off = 32; off >= 1; off >>= 1) eacc += __shfl_xor(eacc, off, 64);
    __shared__ float se[4];
    if (lane == 0) se[wib] = eacc * 0.125f;
    __syncthreads();
    if (threadIdx.x == 0)
        block_energy[blockIdx.x] = se[0] + se[1] + se[2] + se[3];
}

// ---- K3: final energy reduce ----
__global__ __launch_bounds__(256) void energy_reduce_kernel(
    const float* __restrict__ block_energy, float* __restrict__ out, int n)
{
    const int lane = threadIdx.x & 63;
    const int wib  = threadIdx.x >> 6;
    float s = 0.0f;
    for (int i = threadIdx.x; i < n; i += 256) s += block_energy[i];
    #pragma unroll
    for (int off = 32; off >= 1; off >>= 1) s += __shfl_xor(s, off, 64);
    __shared__ float se[4];
    if (lane == 0) se[wib] = s;
    __syncthreads();
    if (threadIdx.x == 0)
        out[0] = (se[0] + se[1] + se[2] + se[3]) * (0.5f * A_F / NUMNEG_F);
}

extern "C" void kernel_launch(void* const* d_in, const int* in_sizes, int n_in,
                              void* d_out, int out_size, void* d_ws, size_t ws_size,
                              hipStream_t stream) {
    const float* x     = (const float*)d_in[0];
    const int*   u_idx = (const int*)d_in[1];
    const int*   v_idx = (const int*)d_in[2];
    float* out = (float*)d_out;
    const int E = in_sizes[1];
    const int N = in_sizes[0] / 64;

    // ws layout
    char* ws = (char*)d_ws;
    int*   counts       = (int*)ws;                          // N ints
    int*   entries      = (int*)(ws + (1 << 20));            // N*CAP ints (~25.6 MB)
    float* block_energy = (float*)(ws + (1 << 20) + (size_t)N * CAP * 4 + (1 << 20));

    // counts must start at zero (400 KB — cheap)
    hipMemsetAsync(counts, 0, (size_t)N * sizeof(int), stream);

    // two-sided bucket fill (+ zero any d_out padding tail)
    fill_kernel<<<4096, 256, 0, stream>>>(u_idx, v_idx, counts, entries,
                                          out, out_size, 1 + N * 64, E);

    node_kernel<<<NBLOCKS, 256, 0, stream>>>(x, counts, entries, out, block_energy, N);

    energy_reduce_kernel<<<1, 256, 0, stream>>>(block_energy, out, NBLOCKS);
}

// Round 7
// 314.633 us; speedup vs baseline: 1.2755x; 1.2755x over previous
//
#include <hip/hip_runtime.h>

#define EPS_F 0.1f
#define A_F 100.0f
#define NUMNEG_F 10.0f
#define EXP_EPS 1.1051709f   // e^0.1; gate: dist<EPS  <=>  (-inner + s) < e^EPS
#define CAP 64               // per-node capacity; one-sided deg ~ Poisson(10)
#define BATCH 16
#define NBLOCKS 4096

// ---- K1: fused zero(d_out) + one-sided bucket fill (R3 baseline, ~110us) ----
__global__ __launch_bounds__(256) void fill_kernel(
    const int* __restrict__ u_idx, const int* __restrict__ v_idx,
    int* __restrict__ counts, int* __restrict__ entries,
    float* __restrict__ out, int out_n, int E)
{
    const int tid = blockIdx.x * blockDim.x + threadIdx.x;
    const int nthreads = gridDim.x * blockDim.x;

    // zero d_out (grad accumulated by atomics; energy overwritten by reduce)
    float4* o4 = (float4*)out;
    const int n4 = out_n >> 2;
    for (int i = tid; i < n4; i += nthreads) o4[i] = float4{0.f, 0.f, 0.f, 0.f};
    if (tid == 0)
        for (int i = n4 * 4; i < out_n; i++) out[i] = 0.f;

    // one-sided bucket fill: edge e listed under u_idx[e] only
    for (int i = tid; i < E; i += nthreads) {
        const int u = u_idx[i];
        const int slot = atomicAdd(&counts[u], 1);
        if (slot < CAP) entries[(size_t)u * CAP + slot] = v_idx[i];
    }
}

// fold-merge: reduce two edges' partial-product vectors one level.
__device__ __forceinline__ float red2(float a, float b, int dist, bool sel) {
    const float fa = a + __shfl_xor(a, dist, 64);
    const float fb = b + __shfl_xor(b, dist, 64);
    return sel ? fb : fa;
}

// 16-edge transpose-reduce + lane-parallel epilogue + scatter.
// Returns nothing; accumulates eacc/gacc, fires v-side atomic rows.
#define PROCESS_BATCH(xuj, vs, xv, bn, gacc)                                   \
    do {                                                                       \
        float p[BATCH];                                                        \
        _Pragma("unroll")                                                      \
        for (int k = 0; k < BATCH; k++) p[k] = (xuj) * (xv)[k];                \
        float q0 = red2(p[0], p[8],  32, m32);                                 \
        float q1 = red2(p[1], p[9],  32, m32);                                 \
        float q2 = red2(p[2], p[10], 32, m32);                                 \
        float q3 = red2(p[3], p[11], 32, m32);                                 \
        float q4 = red2(p[4], p[12], 32, m32);                                 \
        float q5 = red2(p[5], p[13], 32, m32);                                 \
        float q6 = red2(p[6], p[14], 32, m32);                                 \
        float q7 = red2(p[7], p[15], 32, m32);                                 \
        float r0 = red2(q0, q4, 16, m16);                                      \
        float r1 = red2(q1, q5, 16, m16);                                      \
        float r2 = red2(q2, q6, 16, m16);                                      \
        float r3 = red2(q3, q7, 16, m16);                                      \
        float s0 = red2(r0, r2, 8, m8);                                        \
        float s1 = red2(r1, r3, 8, m8);                                        \
        float t0 = red2(s0, s1, 4, m4);                                        \
        t0 += __shfl_xor(t0, 2, 64);                                           \
        t0 += __shfl_xor(t0, 1, 64);                                           \
        const float inner = fminf(t0, -1.0f - 1e-7f);                          \
        const float sq    = __builtin_amdgcn_sqrtf(fmaf(inner, inner, -1.0f)); \
        const float tt    = sq - inner;                                        \
        const bool  act   = (tt < EXP_EPS) & (e4 < (bn));                      \
        const float dist  = __logf(tt);                                        \
        const float delta = act ? (EPS_F - dist) : 0.0f;                       \
        eacc = fmaf(delta, delta, eacc);                                       \
        const float factor = (-(A_F / NUMNEG_F)) * delta *                     \
                             __builtin_amdgcn_rcpf(sq + 1e-9f);                \
        const unsigned long long ball = __ballot(act);                         \
        _Pragma("unroll")                                                      \
        for (int k = 0; k < BATCH; k++) {                                      \
            if ((ball >> (4 * k)) & 1ull) {                                    \
                const float fk = __uint_as_float(                              \
                    __builtin_amdgcn_readlane(__float_as_uint(factor), 4 * k));\
                unsafeAtomicAdd(&grad[(size_t)(vs)[k] * 64 + lane], fk * (xuj));\
                (gacc) = fmaf(fk, (xv)[k], (gacc));                            \
            }                                                                  \
        }                                                                      \
    } while (0)

// ---- K2: PAIRED node kernel. Two adjacent nodes per iteration: 32 gathers
//      in flight per wait, one atomic-completion stall amortized over 2 nodes.
//      Slots >=16 (deg>16, ~3% of nodes) handled in a separate sweep. ----
__global__ __launch_bounds__(256) void node_kernel(
    const float* __restrict__ x,
    const int* __restrict__ counts,
    const int* __restrict__ entries,
    float* __restrict__ out,          // out[0]=energy, out+1 = grad
    float* __restrict__ block_energy,
    int N)
{
    const int lane = threadIdx.x & 63;
    const int wib  = threadIdx.x >> 6;
    const int wave = (blockIdx.x * blockDim.x + threadIdx.x) >> 6;
    const int nwaves = (gridDim.x * blockDim.x) >> 6;
    const float sign = (lane == 0) ? -1.0f : 1.0f;   // Minkowski J
    float* __restrict__ grad = out + 1;

    const bool m32 = (lane & 32) != 0;
    const bool m16 = (lane & 16) != 0;
    const bool m8  = (lane & 8)  != 0;
    const bool m4  = (lane & 4)  != 0;
    const int  e4  = lane >> 2;

    float eacc = 0.0f;   // one-sided, 4x lane-replicated -> *0.25 at the end

    // ---- main paired sweep: slots 0..15 of nodes (uA, uA+1) ----
    int uA = wave * 2;
    const int stride = nwaves * 2;
    int degA = 0, myvA = 0, degB = 0, myvB = 0;
    if (uA < N)     { degA = counts[uA];     myvA = entries[(size_t)uA * CAP + lane]; }
    if (uA + 1 < N) { degB = counts[uA + 1]; myvB = entries[(size_t)(uA + 1) * CAP + lane]; }

    while (uA < N) {
        const int uB = uA + 1;
        const int bnA = min(degA, BATCH);
        const int bnB = min(degB, BATCH);   // 0 if uB >= N
        const int myvA_c = myvA, myvB_c = myvB;

        // xu rows (adjacent) + 32 neighbor-row gathers, all back-to-back
        const float xujA = x[(size_t)uA * 64 + lane] * sign;
        const float xujB = (uB < N) ? x[(size_t)uB * 64 + lane] * sign : 0.0f;

        int vsA[BATCH], vsB[BATCH];
        float xvA[BATCH], xvB[BATCH];
        #pragma unroll
        for (int k = 0; k < BATCH; k++) {
            if (k < bnA) {
                vsA[k] = __builtin_amdgcn_readlane(myvA_c, k);
                xvA[k] = x[(size_t)vsA[k] * 64 + lane];
            } else { vsA[k] = 0; xvA[k] = 0.0f; }
        }
        #pragma unroll
        for (int k = 0; k < BATCH; k++) {
            if (k < bnB) {
                vsB[k] = __builtin_amdgcn_readlane(myvB_c, k);
                xvB[k] = x[(size_t)vsB[k] * 64 + lane];
            } else { vsB[k] = 0; xvB[k] = 0.0f; }
        }

        // prefetch next pair's adjacency (overlaps with compute)
        const int uAn = uA + stride;
        int degA2 = 0, myvA2 = 0, degB2 = 0, myvB2 = 0;
        if (uAn < N)     { degA2 = counts[uAn];     myvA2 = entries[(size_t)uAn * CAP + lane]; }
        if (uAn + 1 < N) { degB2 = counts[uAn + 1]; myvB2 = entries[(size_t)(uAn + 1) * CAP + lane]; }

        // compute + scatter A, then B (B's tree overlaps A's atomics issue)
        float gaccA = 0.0f, gaccB = 0.0f;
        PROCESS_BATCH(xujA, vsA, xvA, bnA, gaccA);
        if (bnA > 0) unsafeAtomicAdd(&grad[(size_t)uA * 64 + lane], gaccA * sign);
        PROCESS_BATCH(xujB, vsB, xvB, bnB, gaccB);
        if (bnB > 0) unsafeAtomicAdd(&grad[(size_t)uB * 64 + lane], gaccB * sign);

        uA = uAn; degA = degA2; myvA = myvA2; degB = degB2; myvB = myvB2;
    }

    // ---- overflow sweep: slots 16..CAP of deg>16 nodes (~3%) ----
    for (int u = wave; u < N; u += nwaves) {
        const int deg = counts[u];
        if (deg <= BATCH) continue;
        const int deg_c = min(deg, CAP);
        const int myv = entries[(size_t)u * CAP + lane];
        const float xuj = x[(size_t)u * 64 + lane] * sign;
        float gacc = 0.0f;
        for (int k0 = BATCH; k0 < deg_c; k0 += BATCH) {
            const int bn = min(BATCH, deg_c - k0);
            int vs[BATCH]; float xv[BATCH];
            #pragma unroll
            for (int k = 0; k < BATCH; k++) {
                if (k < bn) {
                    vs[k] = __builtin_amdgcn_readlane(myv, k0 + k);
                    xv[k] = x[(size_t)vs[k] * 64 + lane];
                } else { vs[k] = 0; xv[k] = 0.0f; }
            }
            PROCESS_BATCH(xuj, vs, xv, bn, gacc);
        }
        unsafeAtomicAdd(&grad[(size_t)u * 64 + lane], gacc * sign);
    }

    // wave-reduce energy (each edge counted on 4 lanes -> *0.25)
    #pragma unroll
    for (int off = 32; off >= 1; off >>= 1) eacc += __shfl_xor(eacc, off, 64);
    __shared__ float se[4];
    if (lane == 0) se[wib] = eacc * 0.25f;
    __syncthreads();
    if (threadIdx.x == 0)
        block_energy[blockIdx.x] = se[0] + se[1] + se[2] + se[3];
}

// ---- K3: final energy reduce ----
__global__ __launch_bounds__(256) void energy_reduce_kernel(
    const float* __restrict__ block_energy, float* __restrict__ out, int n)
{
    const int lane = threadIdx.x & 63;
    const int wib  = threadIdx.x >> 6;
    float s = 0.0f;
    for (int i = threadIdx.x; i < n; i += 256) s += block_energy[i];
    #pragma unroll
    for (int off = 32; off >= 1; off >>= 1) s += __shfl_xor(s, off, 64);
    __shared__ float se[4];
    if (lane == 0) se[wib] = s;
    __syncthreads();
    if (threadIdx.x == 0)
        out[0] = (se[0] + se[1] + se[2] + se[3]) * (0.5f * A_F / NUMNEG_F);
}

extern "C" void kernel_launch(void* const* d_in, const int* in_sizes, int n_in,
                              void* d_out, int out_size, void* d_ws, size_t ws_size,
                              hipStream_t stream) {
    const float* x     = (const float*)d_in[0];
    const int*   u_idx = (const int*)d_in[1];
    const int*   v_idx = (const int*)d_in[2];
    float* out = (float*)d_out;
    const int E = in_sizes[1];
    const int N = in_sizes[0] / 64;

    // ws layout
    char* ws = (char*)d_ws;
    int*   counts       = (int*)ws;                          // N ints
    int*   entries      = (int*)(ws + (1 << 20));            // N*CAP ints (~25.6 MB)
    float* block_energy = (float*)(ws + (1 << 20) + (size_t)N * CAP * 4 + (1 << 20));

    // counts must start at zero (400 KB — cheap)
    hipMemsetAsync(counts, 0, (size_t)N * sizeof(int), stream);

    // fused: zero d_out + one-sided bucket fill
    fill_kernel<<<4096, 256, 0, stream>>>(u_idx, v_idx, counts, entries,
                                          out, out_size, E);

    node_kernel<<<NBLOCKS, 256, 0, stream>>>(x, counts, entries, out, block_energy, N);

    energy_reduce_kernel<<<1, 256, 0, stream>>>(block_energy, out, NBLOCKS);
}